// Round 8
// baseline (133.616 us; speedup 1.0000x reference)
//
#include <hip/hip_runtime.h>
#include <hip/hip_cooperative_groups.h>
#include <math.h>

namespace cg = cooperative_groups;

#define Bn 48
#define Ln 17
#define Dn 256
#define Mn 768        // Bn*(Ln-1)
#define LDA 76        // LDS row stride for phase-1 staging (floats)
#define NBLK 156      // 12 n-tiles x 13 m-tiles
#define NKB 96        // phase-2 blocks: 2 slices x 48 i

// exp(e) for e in [0, ~0.02]; rel err < 3e-15
static __device__ __forceinline__ double pexp(double e) {
  return 1.0 + e*(1.0 + e*(0.5 + e*((1.0/6.0) + e*((1.0/24.0) + e*(1.0/120.0)))));
}

// block-wide sum over 16 waves (1024 threads); safe for back-to-back reuse
static __device__ __forceinline__ double blockReduce16(double v, double* red) {
  __syncthreads();
  #pragma unroll
  for (int o = 32; o > 0; o >>= 1) v += __shfl_down(v, o, 64);
  int lane = threadIdx.x & 63, wid = threadIdx.x >> 6;
  if (lane == 0) red[wid] = v;
  __syncthreads();
  double r = 0.0;
  #pragma unroll
  for (int w = 0; w < 16; ++w) r += red[w];
  return r;
}

// logical row m (0..815: 48 anchors then 768 tokens) -> row in x (B,L,D)
static __device__ __forceinline__ int src_row_m(int m) {
  if (m < Bn) return m * Ln;                 // (b, l=0)
  int t = m - Bn;
  return (t >> 4) * Ln + (t & 15) + 1;       // (b, l=1..16)
}
static __device__ __forceinline__ int src_row_n(int n) {
  return (n >> 4) * Ln + (n & 15) + 1;
}

__global__ __launch_bounds__(1024) void kFused(const float* __restrict__ x,
                                               const int* __restrict__ label,
                                               double* __restrict__ EA,
                                               double* __restrict__ E,
                                               float* __restrict__ out) {
  __shared__ double2 sp[Mn];                 // 12288 B; phase-1 aliases into it
  __shared__ double red[16];
  __shared__ int lab[Bn];

  int tid = threadIdx.x;
  int blk = blockIdx.x;

  // ================= phase 1: one 64x64 tile of exp(S) =================
  {
    float* As = (float*)sp;                  // [16][LDA] = 4864 B
    float* Bs = As + 16 * LDA;               // 4864 B
    float* nA = Bs + 16 * LDA;               // 64 floats
    float* nB = nA + 64;                     // 64 floats (total 10240 B)

    if (blk == 0 && tid == 0) out[0] = 0.f;
    int tn = blk % 12, tm = blk / 12;
    int m0 = tm * 64, n0 = tn * 64;

    // staging threads: tid < 256, same pattern/FP-order as R7 kA
    int r = tid >> 2, cq = tid & 3;
    const float* pa = x;
    const float* pb = x;
    float4 ra = {0,0,0,0}, rb = {0,0,0,0};
    if (tid < 256) {
      int mrow = m0 + r;
      int gm = (mrow < 816) ? src_row_m(mrow) : 0;
      int gn = src_row_n(n0 + r);
      pa = x + gm * Dn + cq * 4;
      pb = x + gn * Dn + cq * 4;
      ra = *(const float4*)pa;
      rb = *(const float4*)pb;
    }
    float ssa = 0.f, ssb = 0.f;
    float c00 = 0.f, c01 = 0.f, c10 = 0.f, c11 = 0.f;
    int tx = tid & 31, ty = tid >> 5;        // 32x32 threads, 2x2 outputs each

    for (int t = 0; t < 16; ++t) {
      __syncthreads();
      if (tid < 256) {
        int kb = cq * 4;
        As[(kb+0)*LDA + r] = ra.x; As[(kb+1)*LDA + r] = ra.y;
        As[(kb+2)*LDA + r] = ra.z; As[(kb+3)*LDA + r] = ra.w;
        Bs[(kb+0)*LDA + r] = rb.x; Bs[(kb+1)*LDA + r] = rb.y;
        Bs[(kb+2)*LDA + r] = rb.z; Bs[(kb+3)*LDA + r] = rb.w;
        ssa += ra.x*ra.x + ra.y*ra.y + ra.z*ra.z + ra.w*ra.w;
        ssb += rb.x*rb.x + rb.y*rb.y + rb.z*rb.z + rb.w*rb.w;
      }
      __syncthreads();
      if (tid < 256 && t < 15) {             // prefetch next k-slab
        ra = *(const float4*)(pa + (t + 1) * 16);
        rb = *(const float4*)(pb + (t + 1) * 16);
      }
      #pragma unroll
      for (int k = 0; k < 16; ++k) {
        float a0 = As[k*LDA + ty*2], a1 = As[k*LDA + ty*2 + 1];
        float b0 = Bs[k*LDA + tx*2], b1 = Bs[k*LDA + tx*2 + 1];
        c00 = fmaf(a0, b0, c00); c01 = fmaf(a0, b1, c01);
        c10 = fmaf(a1, b0, c10); c11 = fmaf(a1, b1, c11);
      }
    }
    if (tid < 256) {                         // per-row sum of squares
      ssa += __shfl_xor(ssa, 1, 64); ssa += __shfl_xor(ssa, 2, 64);
      ssb += __shfl_xor(ssb, 1, 64); ssb += __shfl_xor(ssb, 2, 64);
      if (cq == 0) { nA[r] = ssa; nB[r] = ssb; }
    }
    __syncthreads();
    double ia0 = 1.0 / sqrt((double)nA[ty*2]);
    double ia1 = 1.0 / sqrt((double)nA[ty*2 + 1]);
    double ib0 = 1.0 / sqrt((double)nB[tx*2]);
    double ib1 = 1.0 / sqrt((double)nB[tx*2 + 1]);
    float cv[2][2] = {{c00, c01}, {c10, c11}};
    double iav[2] = {ia0, ia1}, ibv[2] = {ib0, ib1};
    #pragma unroll
    for (int i2 = 0; i2 < 2; ++i2) {
      int m = m0 + ty*2 + i2;
      if (m >= 816) continue;
      #pragma unroll
      for (int j2 = 0; j2 < 2; ++j2) {
        int n = n0 + tx*2 + j2;
        double ev = exp((double)cv[i2][j2] * iav[i2] * ibv[j2]);   // T = 1.0
        if (m < Bn) EA[m * Mn + n] = ev;
        else        E[(m - Bn) * Mn + n] = ev;
      }
    }
  }

  // ================= grid-wide barrier =================
  cg::this_grid().sync();

  if (blk >= NKB) return;

  // ================= phase 2: kB body for (slice, i) =================
  int slice = blk & 1, i = blk >> 1;
  int lane = tid & 63, w = tid >> 6;
  if (tid < Bn) lab[tid] = label[tid];
  __syncthreads();
  int li = lab[i];

  // ---- per-i setup from EA row (tid<768 holds one element in-register) ----
  bool has = (tid < Mn);
  bool neg = has && (lab[tid >> 4] != li);
  double eav = has ? EA[i * Mn + tid] : 0.0;
  double s1 = blockReduce16(neg ? eav : 0.0, red);
  double ci = 1.0 / s1;                      // exp(-log_denom)
  double a = ci * eav;
  double p = pexp(a);
  if (has) { sp[tid].x = neg ? a : 0.0; sp[tid].y = neg ? p : 0.0; }
  double t2a = blockReduce16(neg ? p : 0.0, red);
  double t2b = blockReduce16(neg ? p * a : 0.0, red);
  double inv_s2 = 1.0 / t2a;
  double Evi = t2b * inv_s2;
  unsigned long long nm = __ballot(lane < Bn && lab[lane] != li);
  int cnt = 64 - __popcll(nm | 0xFFFF000000000000ull);   // same-label batches

  // ---- sweep positive bj's of this slice; wave w handles j = bj*16 + w ----
  int kb0 = lane >> 4;
  double tsum = 0.0;
  for (int bj = slice; bj < Bn; bj += 2) {
    if (lab[bj] != li) continue;             // uniform LDS test, no divergence
    const double* Ej = E + (bj * 16 + w) * Mn + lane;
    double Evv[12];
    #pragma unroll
    for (int it = 0; it < 12; ++it) Evv[it] = Ej[64 * it];
    double A = 0.0, Bv = 0.0, C = 0.0, D2 = 0.0;
    #pragma unroll
    for (int it = 0; it < 12; ++it) {
      double m = (double)((nm >> (kb0 + 4 * it)) & 1ull);
      double e = ci * Evv[it];
      double wx = pexp(e);
      double wm = wx * m;
      double2 s = sp[lane + 64 * it];
      A  = fma(wm, e, A);
      Bv = fma(wx, s.x, Bv);                 // s.x pre-masked
      C += wm;
      D2 = fma(s.y, e, D2);                  // s.y pre-masked
    }
    #pragma unroll
    for (int o = 32; o > 0; o >>= 1) {
      A  += __shfl_xor(A,  o, 64);
      Bv += __shfl_xor(Bv, o, 64);
      C  += __shfl_xor(C,  o, 64);
      D2 += __shfl_xor(D2, o, 64);
    }
    tsum += (A - Bv) / C - D2 * inv_s2 + Evi;
  }

  // ---- fold 16 wave partials, one float atomic per block ----
  __syncthreads();
  if (lane == 0) red[w] = tsum;
  __syncthreads();
  if (tid == 0) {
    double s = 0.0;
    #pragma unroll
    for (int ww = 0; ww < 16; ++ww) s += red[ww];
    // contribution = 0.5 * s / (Bn * P_i), P_i = 16*cnt  ->  s / (1536*cnt)
    atomicAdd(out, (float)(s / (1536.0 * (double)cnt)));
  }
}

extern "C" void kernel_launch(void* const* d_in, const int* in_sizes, int n_in,
                              void* d_out, int out_size, void* d_ws, size_t ws_size,
                              hipStream_t stream) {
  const float* x   = (const float*)d_in[0];
  const int* label = (const int*)d_in[1];
  float* out = (float*)d_out;

  char* ws = (char*)d_ws;
  size_t off = 0;
  auto alloc = [&](size_t bytes) -> void* {
    void* p = ws + off;
    off = (off + bytes + 255) & ~(size_t)255;
    return p;
  };
  double* EA = (double*)alloc((size_t)Bn * Mn * sizeof(double));
  double* E  = (double*)alloc((size_t)Mn * Mn * sizeof(double));

  void* args[] = {(void*)&x, (void*)&label, (void*)&EA, (void*)&E, (void*)&out};
  hipLaunchCooperativeKernel((const void*)kFused, dim3(NBLK), dim3(1024),
                             args, 0, stream);
}

// Round 9
// 131.000 us; speedup vs baseline: 1.0200x; 1.0200x over previous
//
#include <hip/hip_runtime.h>
#include <hip/hip_cooperative_groups.h>
#include <math.h>

namespace cg = cooperative_groups;

#define Bn 48
#define Ln 17
#define Dn 256
#define Mn 768        // Bn*(Ln-1)
#define LDA 76        // LDS row stride for phase-1 staging (floats)
#define NTILE 156     // 12 n-tiles x 13 m-tiles
#define NS 5          // phase-2 slices
#define NBLK 240      // NS * Bn; >= NTILE

// exp(e) for e in [0, ~0.02]; rel err < 3e-15
static __device__ __forceinline__ double pexp(double e) {
  return 1.0 + e*(1.0 + e*(0.5 + e*((1.0/6.0) + e*((1.0/24.0) + e*(1.0/120.0)))));
}

// block-wide sum over 4 waves (256 threads); safe for back-to-back reuse
static __device__ __forceinline__ double bRed4(double v, double* red) {
  __syncthreads();
  #pragma unroll
  for (int o = 32; o > 0; o >>= 1) v += __shfl_down(v, o, 64);
  int lane = threadIdx.x & 63, wid = threadIdx.x >> 6;
  if (lane == 0) red[wid] = v;
  __syncthreads();
  return red[0] + red[1] + red[2] + red[3];
}

// logical row m (0..815: 48 anchors then 768 tokens) -> row in x (B,L,D)
static __device__ __forceinline__ int src_row_m(int m) {
  if (m < Bn) return m * Ln;                 // (b, l=0)
  int t = m - Bn;
  return (t >> 4) * Ln + (t & 15) + 1;       // (b, l=1..16)
}
static __device__ __forceinline__ int src_row_n(int n) {
  return (n >> 4) * Ln + (n & 15) + 1;
}

__global__ __launch_bounds__(256) void kFused(const float* __restrict__ x,
                                              const int* __restrict__ label,
                                              double* __restrict__ EA,
                                              double* __restrict__ E,
                                              float* __restrict__ out) {
  // phase-1 LDS (R7 kA layout)
  __shared__ float As[16][LDA];
  __shared__ float Bs[16][LDA];
  __shared__ float nA[64], nB[64];
  // phase-2 LDS
  __shared__ double2 sp[Mn];                 // {a masked, pexp(a) masked}
  __shared__ double red[4];
  __shared__ int lab[Bn];

  int tid = threadIdx.x;
  int blk = blockIdx.x;

  // ================= phase 1: one 64x64 tile of exp(S) (R7 kA verbatim) ======
  if (blk < NTILE) {
    if (blk == 0 && tid == 0) out[0] = 0.f;
    int tn = blk % 12, tm = blk / 12;
    int m0 = tm * 64, n0 = tn * 64;
    int r  = tid >> 2, cq = tid & 3;
    int mrow = m0 + r;
    int gm = (mrow < 816) ? src_row_m(mrow) : 0;
    int gn = src_row_n(n0 + r);
    const float* pa = x + gm * Dn + cq * 4;
    const float* pb = x + gn * Dn + cq * 4;
    float4 ra = *(const float4*)pa;
    float4 rb = *(const float4*)pb;
    float ssa = 0.f, ssb = 0.f;
    float c[4][4];
    #pragma unroll
    for (int i = 0; i < 4; ++i)
      #pragma unroll
      for (int j = 0; j < 4; ++j) c[i][j] = 0.f;
    int tx = tid & 15, ty = tid >> 4;

    for (int t = 0; t < 16; ++t) {
      __syncthreads();
      int kb = cq * 4;
      As[kb+0][r] = ra.x; As[kb+1][r] = ra.y; As[kb+2][r] = ra.z; As[kb+3][r] = ra.w;
      Bs[kb+0][r] = rb.x; Bs[kb+1][r] = rb.y; Bs[kb+2][r] = rb.z; Bs[kb+3][r] = rb.w;
      ssa += ra.x*ra.x + ra.y*ra.y + ra.z*ra.z + ra.w*ra.w;
      ssb += rb.x*rb.x + rb.y*rb.y + rb.z*rb.z + rb.w*rb.w;
      __syncthreads();
      if (t < 15) {                          // prefetch next k-slab
        ra = *(const float4*)(pa + (t + 1) * 16);
        rb = *(const float4*)(pb + (t + 1) * 16);
      }
      #pragma unroll
      for (int k = 0; k < 16; ++k) {
        float4 a4 = *(const float4*)&As[k][ty * 4];
        float4 b4 = *(const float4*)&Bs[k][tx * 4];
        float av[4] = {a4.x, a4.y, a4.z, a4.w};
        float bv[4] = {b4.x, b4.y, b4.z, b4.w};
        #pragma unroll
        for (int i = 0; i < 4; ++i)
          #pragma unroll
          for (int j = 0; j < 4; ++j) c[i][j] = fmaf(av[i], bv[j], c[i][j]);
      }
    }
    ssa += __shfl_xor(ssa, 1, 64); ssa += __shfl_xor(ssa, 2, 64);
    ssb += __shfl_xor(ssb, 1, 64); ssb += __shfl_xor(ssb, 2, 64);
    if (cq == 0) { nA[r] = ssa; nB[r] = ssb; }
    __syncthreads();
    double ia[4], ib[4];
    #pragma unroll
    for (int i = 0; i < 4; ++i) ia[i] = 1.0 / sqrt((double)nA[ty * 4 + i]);
    #pragma unroll
    for (int j = 0; j < 4; ++j) ib[j] = 1.0 / sqrt((double)nB[tx * 4 + j]);
    #pragma unroll
    for (int i = 0; i < 4; ++i) {
      int m = m0 + ty * 4 + i;
      if (m < 816) {
        #pragma unroll
        for (int j = 0; j < 4; ++j) {
          int n = n0 + tx * 4 + j;
          double ev = exp((double)c[i][j] * ia[i] * ib[j]);   // T = 1.0
          if (m < Bn) EA[m * Mn + n] = ev;
          else        E[(m - Bn) * Mn + n] = ev;
        }
      }
    }
  }

  // ================= grid-wide barrier =================
  cg::this_grid().sync();

  // ================= phase 2: (slice, i), 4 waves, all 240 blocks active =====
  int slice = blk / Bn, i = blk % Bn;
  int lane = tid & 63, w = tid >> 6;
  if (tid < Bn) lab[tid] = label[tid];
  __syncthreads();
  int li = lab[i];

  // ---- per-i setup from EA row: 3 strided passes ----
  double ev3[3];
  bool ng3[3];
  double s1l = 0.0;
  #pragma unroll
  for (int rr = 0; rr < 3; ++rr) {
    int k = tid + 256 * rr;
    ng3[rr] = (lab[k >> 4] != li);
    ev3[rr] = EA[i * Mn + k];
    if (ng3[rr]) s1l += ev3[rr];
  }
  double s1 = bRed4(s1l, red);
  double ci = 1.0 / s1;                      // exp(-log_denom)
  double t2al = 0.0, t2bl = 0.0;
  #pragma unroll
  for (int rr = 0; rr < 3; ++rr) {
    int k = tid + 256 * rr;
    double a = ci * ev3[rr];
    double p = pexp(a);
    sp[k].x = ng3[rr] ? a : 0.0;
    sp[k].y = ng3[rr] ? p : 0.0;
    if (ng3[rr]) { t2al += p; t2bl += p * a; }
  }
  double t2a = bRed4(t2al, red);
  double t2b = bRed4(t2bl, red);
  double inv_s2 = 1.0 / t2a;
  double Evi = t2b * inv_s2;
  unsigned long long nm = __ballot(lane < Bn && lab[lane] != li);
  int cnt = 64 - __popcll(nm | 0xFFFF000000000000ull);   // same-label batches

  // ---- sweep positive bj's of this slice; wave w handles 4 j per bj ----
  int kb0 = lane >> 4;
  double tsum = 0.0;
  for (int bj = slice; bj < Bn; bj += NS) {
    if (lab[bj] != li) continue;             // uniform LDS test, no divergence
    #pragma unroll
    for (int jj = 0; jj < 4; ++jj) {
      int j = bj * 16 + w * 4 + jj;
      const double* Ej = E + j * Mn + lane;
      double Evv[12];
      #pragma unroll
      for (int it = 0; it < 12; ++it) Evv[it] = Ej[64 * it];
      double A = 0.0, Bv = 0.0, C = 0.0, D2 = 0.0;
      #pragma unroll
      for (int it = 0; it < 12; ++it) {
        double m = (double)((nm >> (kb0 + 4 * it)) & 1ull);
        double e = ci * Evv[it];
        double wx = pexp(e);
        double wm = wx * m;
        double2 s = sp[lane + 64 * it];
        A  = fma(wm, e, A);
        Bv = fma(wx, s.x, Bv);               // s.x pre-masked
        C += wm;
        D2 = fma(s.y, e, D2);                // s.y pre-masked
      }
      #pragma unroll
      for (int o = 32; o > 0; o >>= 1) {
        A  += __shfl_xor(A,  o, 64);
        Bv += __shfl_xor(Bv, o, 64);
        C  += __shfl_xor(C,  o, 64);
        D2 += __shfl_xor(D2, o, 64);
      }
      tsum += (A - Bv) / C - D2 * inv_s2 + Evi;
    }
  }

  // ---- fold 4 wave partials, one float atomic per block ----
  __syncthreads();
  if (lane == 0) red[w] = tsum;
  __syncthreads();
  if (tid == 0) {
    double s = red[0] + red[1] + red[2] + red[3];
    // contribution = 0.5 * s / (Bn * P_i), P_i = 16*cnt  ->  s / (1536*cnt)
    atomicAdd(out, (float)(s / (1536.0 * (double)cnt)));
  }
}

extern "C" void kernel_launch(void* const* d_in, const int* in_sizes, int n_in,
                              void* d_out, int out_size, void* d_ws, size_t ws_size,
                              hipStream_t stream) {
  const float* x   = (const float*)d_in[0];
  const int* label = (const int*)d_in[1];
  float* out = (float*)d_out;

  char* ws = (char*)d_ws;
  size_t off = 0;
  auto alloc = [&](size_t bytes) -> void* {
    void* p = ws + off;
    off = (off + bytes + 255) & ~(size_t)255;
    return p;
  };
  double* EA = (double*)alloc((size_t)Bn * Mn * sizeof(double));
  double* E  = (double*)alloc((size_t)Mn * Mn * sizeof(double));

  void* args[] = {(void*)&x, (void*)&label, (void*)&EA, (void*)&E, (void*)&out};
  hipLaunchCooperativeKernel((const void*)kFused, dim3(NBLK), dim3(256),
                             args, 0, stream);
}

// Round 10
// 89.549 us; speedup vs baseline: 1.4921x; 1.4629x over previous
//
#include <hip/hip_runtime.h>
#include <math.h>

#define Bn 48
#define Ln 17
#define Dn 256
#define Mn 768        // Bn*(Ln-1)
#define NS 2          // kB slices per i (blocks = NS*Bn, all active)
#define LDA 76        // LDS row stride for kA staging

// exp(e) for e in [0, ~0.02]; rel err < 3e-15
static __device__ __forceinline__ double pexp(double e) {
  return 1.0 + e*(1.0 + e*(0.5 + e*((1.0/6.0) + e*((1.0/24.0) + e*(1.0/120.0)))));
}

// block-wide sum over 16 waves (1024 threads); safe for back-to-back reuse
static __device__ __forceinline__ double blockReduce16(double v, double* red) {
  __syncthreads();
  #pragma unroll
  for (int o = 32; o > 0; o >>= 1) v += __shfl_down(v, o, 64);
  int lane = threadIdx.x & 63, wid = threadIdx.x >> 6;
  if (lane == 0) red[wid] = v;
  __syncthreads();
  double r = 0.0;
  #pragma unroll
  for (int w = 0; w < 16; ++w) r += red[w];
  return r;
}

// logical row m (0..815: 48 anchors then 768 tokens) -> row in x (B,L,D)
static __device__ __forceinline__ int src_row_m(int m) {
  if (m < Bn) return m * Ln;                 // (b, l=0)
  int t = m - Bn;
  return (t >> 4) * Ln + (t & 15) + 1;       // (b, l=1..16)
}
static __device__ __forceinline__ int src_row_n(int n) {
  return (n >> 4) * Ln + (n & 15) + 1;
}

// ---------- kA: fused normalize + GEMM + exp epilogue (float out); zero out ----
__global__ __launch_bounds__(256) void kA_gemm(const float* __restrict__ x,
                                               float* __restrict__ EA,
                                               float* __restrict__ E,
                                               float* __restrict__ out) {
  __shared__ float As[16][LDA];
  __shared__ float Bs[16][LDA];
  __shared__ float nA[64], nB[64];
  int tid = threadIdx.x;
  if (blockIdx.x == 0 && blockIdx.y == 0 && tid == 0) out[0] = 0.f;
  int m0 = blockIdx.y * 64, n0 = blockIdx.x * 64;
  int r  = tid >> 2, cq = tid & 3;
  int mrow = m0 + r;
  int gm = (mrow < 816) ? src_row_m(mrow) : 0;
  int gn = src_row_n(n0 + r);
  const float* pa = x + gm * Dn + cq * 4;
  const float* pb = x + gn * Dn + cq * 4;
  float4 ra = *(const float4*)pa;
  float4 rb = *(const float4*)pb;
  float ssa = 0.f, ssb = 0.f;
  float c[4][4];
  #pragma unroll
  for (int i = 0; i < 4; ++i)
    #pragma unroll
    for (int j = 0; j < 4; ++j) c[i][j] = 0.f;
  int tx = tid & 15, ty = tid >> 4;

  for (int t = 0; t < 16; ++t) {
    __syncthreads();
    int kb = cq * 4;
    As[kb+0][r] = ra.x; As[kb+1][r] = ra.y; As[kb+2][r] = ra.z; As[kb+3][r] = ra.w;
    Bs[kb+0][r] = rb.x; Bs[kb+1][r] = rb.y; Bs[kb+2][r] = rb.z; Bs[kb+3][r] = rb.w;
    ssa += ra.x*ra.x + ra.y*ra.y + ra.z*ra.z + ra.w*ra.w;
    ssb += rb.x*rb.x + rb.y*rb.y + rb.z*rb.z + rb.w*rb.w;
    __syncthreads();
    if (t < 15) {                            // prefetch next k-slab
      ra = *(const float4*)(pa + (t + 1) * 16);
      rb = *(const float4*)(pb + (t + 1) * 16);
    }
    #pragma unroll
    for (int k = 0; k < 16; ++k) {
      float4 a4 = *(const float4*)&As[k][ty * 4];
      float4 b4 = *(const float4*)&Bs[k][tx * 4];
      float av[4] = {a4.x, a4.y, a4.z, a4.w};
      float bv[4] = {b4.x, b4.y, b4.z, b4.w};
      #pragma unroll
      for (int i = 0; i < 4; ++i)
        #pragma unroll
        for (int j = 0; j < 4; ++j) c[i][j] = fmaf(av[i], bv[j], c[i][j]);
    }
  }
  ssa += __shfl_xor(ssa, 1, 64); ssa += __shfl_xor(ssa, 2, 64);
  ssb += __shfl_xor(ssb, 1, 64); ssb += __shfl_xor(ssb, 2, 64);
  if (cq == 0) { nA[r] = ssa; nB[r] = ssb; }
  __syncthreads();
  double ia[4], ib[4];
  #pragma unroll
  for (int i = 0; i < 4; ++i) ia[i] = 1.0 / sqrt((double)nA[ty * 4 + i]);
  #pragma unroll
  for (int j = 0; j < 4; ++j) ib[j] = 1.0 / sqrt((double)nB[tx * 4 + j]);
  #pragma unroll
  for (int i = 0; i < 4; ++i) {
    int m = m0 + ty * 4 + i;
    if (m < 816) {
      #pragma unroll
      for (int j = 0; j < 4; ++j) {
        int n = n0 + tx * 4 + j;
        float s = (float)((double)c[i][j] * ia[i] * ib[j]);   // T = 1.0
        float ev = __expf(s);
        if (m < Bn) EA[m * Mn + n] = ev;
        else        E[(m - Bn) * Mn + n] = ev;
      }
    }
  }
}

// ---------- kB: grid (NS, Bn) — per-i setup + sweep positive bj; atomic out ----
// t(i,j) = (A - Bv)/C - D2*inv_s2 + Evi
__global__ __launch_bounds__(1024, 2) void kB_i(const float* __restrict__ EA,
                                                const float* __restrict__ E,
                                                const int* __restrict__ label,
                                                float* __restrict__ out) {
  __shared__ double2 sp[Mn];                 // {a masked, pexp(a) masked}
  __shared__ double red[16];
  __shared__ int lab[Bn];
  int slice = blockIdx.x, i = blockIdx.y;
  int tid = threadIdx.x;
  int lane = tid & 63, w = tid >> 6;
  if (tid < Bn) lab[tid] = label[tid];
  __syncthreads();
  int li = lab[i];

  // ---- per-i setup from EA row (tid<768 holds one element in-register) ----
  bool has = (tid < Mn);
  bool neg = has && (lab[tid >> 4] != li);
  double eav = has ? (double)EA[i * Mn + tid] : 0.0;
  double s1 = blockReduce16(neg ? eav : 0.0, red);
  double ci = 1.0 / s1;                      // exp(-log_denom)
  double a = ci * eav;
  double p = pexp(a);
  if (has) { sp[tid].x = neg ? a : 0.0; sp[tid].y = neg ? p : 0.0; }
  double t2a = blockReduce16(neg ? p : 0.0, red);
  double t2b = blockReduce16(neg ? p * a : 0.0, red);
  double inv_s2 = 1.0 / t2a;
  double Evi = t2b * inv_s2;
  unsigned long long nm = __ballot(lane < Bn && lab[lane] != li);
  int cnt = 64 - __popcll(nm | 0xFFFF000000000000ull);   // same-label batches

  // ---- sweep positive bj's of this slice; wave w handles j = bj*16 + w ----
  int kb0 = lane >> 4;
  double tsum = 0.0;
  for (int bj = slice; bj < Bn; bj += NS) {
    if (lab[bj] != li) continue;             // uniform LDS test, no divergence
    const float* Ej = E + (bj * 16 + w) * Mn + lane;
    float Evv[12];
    #pragma unroll
    for (int it = 0; it < 12; ++it) Evv[it] = Ej[64 * it];
    double A = 0.0, Bv = 0.0, C = 0.0, D2 = 0.0;
    #pragma unroll
    for (int it = 0; it < 12; ++it) {
      double m = (double)((nm >> (kb0 + 4 * it)) & 1ull);
      double e = ci * (double)Evv[it];
      double wx = pexp(e);
      double wm = wx * m;
      double2 s = sp[lane + 64 * it];
      A  = fma(wm, e, A);
      Bv = fma(wx, s.x, Bv);                 // s.x pre-masked
      C += wm;
      D2 = fma(s.y, e, D2);                  // s.y pre-masked
    }
    #pragma unroll
    for (int o = 32; o > 0; o >>= 1) {
      A  += __shfl_xor(A,  o, 64);
      Bv += __shfl_xor(Bv, o, 64);
      C  += __shfl_xor(C,  o, 64);
      D2 += __shfl_xor(D2, o, 64);
    }
    tsum += (A - Bv) / C - D2 * inv_s2 + Evi;
  }

  // ---- fold 16 wave partials, one float atomic per block ----
  __syncthreads();
  if (lane == 0) red[w] = tsum;
  __syncthreads();
  if (tid == 0) {
    double s = 0.0;
    #pragma unroll
    for (int ww = 0; ww < 16; ++ww) s += red[ww];
    // contribution = 0.5 * s / (Bn * P_i), P_i = 16*cnt  ->  s / (1536*cnt)
    atomicAdd(out, (float)(s / (1536.0 * (double)cnt)));
  }
}

extern "C" void kernel_launch(void* const* d_in, const int* in_sizes, int n_in,
                              void* d_out, int out_size, void* d_ws, size_t ws_size,
                              hipStream_t stream) {
  const float* x   = (const float*)d_in[0];
  const int* label = (const int*)d_in[1];
  float* out = (float*)d_out;

  char* ws = (char*)d_ws;
  size_t off = 0;
  auto alloc = [&](size_t bytes) -> void* {
    void* p = ws + off;
    off = (off + bytes + 255) & ~(size_t)255;
    return p;
  };
  float* EA = (float*)alloc((size_t)Bn * Mn * sizeof(float));
  float* E  = (float*)alloc((size_t)Mn * Mn * sizeof(float));

  kA_gemm<<<dim3(12, 13), 256, 0, stream>>>(x, EA, E, out);
  kB_i<<<dim3(NS, Bn), 1024, 0, stream>>>(EA, E, label, out);
}

// Round 11
// 83.327 us; speedup vs baseline: 1.6035x; 1.0747x over previous
//
#include <hip/hip_runtime.h>
#include <math.h>

#define Bn 48
#define Ln 17
#define Dn 256
#define Mn 768        // Bn*(Ln-1)
#define NS 2          // kB slices per i (blocks = NS*Bn, all active)
#define LDK 264       // LDS row stride in shorts for bf16 tiles (256 + 8)

typedef __attribute__((ext_vector_type(8))) short frag8;   // 8 bf16 = 4 VGPR
typedef __attribute__((ext_vector_type(4))) float fragc;   // C/D accum
typedef __attribute__((ext_vector_type(4))) short short4v;

// float -> bf16 (RNE) as raw short
static __device__ __forceinline__ short f2bf(float f) {
  unsigned u = __float_as_uint(f);
  unsigned r = (u + 0x7FFFu + ((u >> 16) & 1u)) >> 16;
  return (short)r;
}
static __device__ __forceinline__ float bf2f(short h) {
  return __uint_as_float(((unsigned)(unsigned short)h) << 16);
}

// exp(e) for e in [0, ~0.02]; rel err < 3e-15
static __device__ __forceinline__ double pexp(double e) {
  return 1.0 + e*(1.0 + e*(0.5 + e*((1.0/6.0) + e*((1.0/24.0) + e*(1.0/120.0)))));
}

// block-wide sum over 16 waves (1024 threads); safe for back-to-back reuse
static __device__ __forceinline__ double blockReduce16(double v, double* red) {
  __syncthreads();
  #pragma unroll
  for (int o = 32; o > 0; o >>= 1) v += __shfl_down(v, o, 64);
  int lane = threadIdx.x & 63, wid = threadIdx.x >> 6;
  if (lane == 0) red[wid] = v;
  __syncthreads();
  double r = 0.0;
  #pragma unroll
  for (int w = 0; w < 16; ++w) r += red[w];
  return r;
}

// logical row m (0..815: 48 anchors then 768 tokens) -> row in x (B,L,D)
static __device__ __forceinline__ int src_row_m(int m) {
  if (m < Bn) return m * Ln;                 // (b, l=0)
  int t = m - Bn;
  return (t >> 4) * Ln + (t & 15) + 1;       // (b, l=1..16)
}
static __device__ __forceinline__ int src_row_n(int n) {
  return (n >> 4) * Ln + (n & 15) + 1;
}

// ---------- kA: normalize+GEMM via bf16 hi/lo split MFMA + exp epilogue ------
// 64x64 tile, 256 threads (4 waves); wave w -> m-strip w*16..w*16+15.
__global__ __launch_bounds__(256) void kA_gemm(const float* __restrict__ x,
                                               float* __restrict__ EA,
                                               float* __restrict__ E,
                                               float* __restrict__ out) {
  __shared__ short Ahi[64 * LDK];
  __shared__ short Alo[64 * LDK];
  __shared__ short Bhi[64 * LDK];
  __shared__ short Blo[64 * LDK];
  __shared__ float nA[64], nB[64];
  int tid = threadIdx.x;
  if (blockIdx.x == 0 && blockIdx.y == 0 && tid == 0) out[0] = 0.f;
  int m0 = blockIdx.y * 64, n0 = blockIdx.x * 64;

  // ---- staging: thread t -> row r = t>>2, 64-col chunk cq = t&3 ----
  {
    int r = tid >> 2, cq = tid & 3;
    int mrow = m0 + r;
    int gm = (mrow < 816) ? src_row_m(mrow) : 0;
    int gn = src_row_n(n0 + r);
    const float4* pa = (const float4*)(x + gm * Dn) + cq * 16;
    const float4* pb = (const float4*)(x + gn * Dn) + cq * 16;
    float ssa = 0.f, ssb = 0.f;
    #pragma unroll
    for (int c4 = 0; c4 < 16; ++c4) {
      float4 fa = pa[c4];
      float4 fb = pb[c4];
      ssa += fa.x*fa.x + fa.y*fa.y + fa.z*fa.z + fa.w*fa.w;
      ssb += fb.x*fb.x + fb.y*fb.y + fb.z*fb.z + fb.w*fb.w;
      int col = cq * 64 + c4 * 4;
      short4v ah, al, bh, bl;
      ah.x = f2bf(fa.x); al.x = f2bf(fa.x - bf2f(ah.x));
      ah.y = f2bf(fa.y); al.y = f2bf(fa.y - bf2f(ah.y));
      ah.z = f2bf(fa.z); al.z = f2bf(fa.z - bf2f(ah.z));
      ah.w = f2bf(fa.w); al.w = f2bf(fa.w - bf2f(ah.w));
      bh.x = f2bf(fb.x); bl.x = f2bf(fb.x - bf2f(bh.x));
      bh.y = f2bf(fb.y); bl.y = f2bf(fb.y - bf2f(bh.y));
      bh.z = f2bf(fb.z); bl.z = f2bf(fb.z - bf2f(bh.z));
      bh.w = f2bf(fb.w); bl.w = f2bf(fb.w - bf2f(bh.w));
      *(short4v*)&Ahi[r * LDK + col] = ah;
      *(short4v*)&Alo[r * LDK + col] = al;
      *(short4v*)&Bhi[r * LDK + col] = bh;
      *(short4v*)&Blo[r * LDK + col] = bl;
    }
    ssa += __shfl_xor(ssa, 1, 64); ssa += __shfl_xor(ssa, 2, 64);
    ssb += __shfl_xor(ssb, 1, 64); ssb += __shfl_xor(ssb, 2, 64);
    if ((tid & 3) == 0) { nA[r] = ssa; nB[r] = ssb; }
  }
  __syncthreads();

  // ---- MFMA: wave w computes rows w*16..+15 x all 64 cols ----
  int lane = tid & 63, w = tid >> 6;
  int ml = lane & 15, q = lane >> 4;
  fragc acc[4];
  #pragma unroll
  for (int s = 0; s < 4; ++s) acc[s] = (fragc){0.f, 0.f, 0.f, 0.f};
  int arow = (w * 16 + ml) * LDK;
  #pragma unroll
  for (int s = 0; s < 8; ++s) {
    int ko = s * 32 + q * 8;
    frag8 ah = *(const frag8*)&Ahi[arow + ko];
    frag8 al = *(const frag8*)&Alo[arow + ko];
    #pragma unroll
    for (int sub = 0; sub < 4; ++sub) {
      int brow = (sub * 16 + ml) * LDK;
      frag8 bh = *(const frag8*)&Bhi[brow + ko];
      frag8 bl = *(const frag8*)&Blo[brow + ko];
      acc[sub] = __builtin_amdgcn_mfma_f32_16x16x32_bf16(ah, bh, acc[sub], 0, 0, 0);
      acc[sub] = __builtin_amdgcn_mfma_f32_16x16x32_bf16(ah, bl, acc[sub], 0, 0, 0);
      acc[sub] = __builtin_amdgcn_mfma_f32_16x16x32_bf16(al, bh, acc[sub], 0, 0, 0);
    }
  }

  // ---- epilogue: C/D layout col=lane&15, row=q*4+reg; fp64 scale + __expf ----
  double ia[4], ib[4];
  #pragma unroll
  for (int rg = 0; rg < 4; ++rg) ia[rg] = 1.0 / sqrt((double)nA[w * 16 + q * 4 + rg]);
  #pragma unroll
  for (int sub = 0; sub < 4; ++sub) ib[sub] = 1.0 / sqrt((double)nB[sub * 16 + ml]);
  #pragma unroll
  for (int sub = 0; sub < 4; ++sub) {
    int n = n0 + sub * 16 + ml;
    #pragma unroll
    for (int rg = 0; rg < 4; ++rg) {
      int m = m0 + w * 16 + q * 4 + rg;
      if (m < 816) {
        float s = (float)((double)acc[sub][rg] * ia[rg] * ib[sub]);   // T = 1.0
        float ev = __expf(s);
        if (m < Bn) EA[m * Mn + n] = ev;
        else        E[(m - Bn) * Mn + n] = ev;
      }
    }
  }
}

// ---------- kB: grid (NS, Bn) — per-i setup + sweep positive bj; atomic out ----
// t(i,j) = (A - Bv)/C - D2*inv_s2 + Evi
__global__ __launch_bounds__(1024, 2) void kB_i(const float* __restrict__ EA,
                                                const float* __restrict__ E,
                                                const int* __restrict__ label,
                                                float* __restrict__ out) {
  __shared__ double2 sp[Mn];                 // {a masked, pexp(a) masked}
  __shared__ double red[16];
  __shared__ int lab[Bn];
  int slice = blockIdx.x, i = blockIdx.y;
  int tid = threadIdx.x;
  int lane = tid & 63, w = tid >> 6;
  if (tid < Bn) lab[tid] = label[tid];
  __syncthreads();
  int li = lab[i];

  // ---- per-i setup from EA row (tid<768 holds one element in-register) ----
  bool has = (tid < Mn);
  bool neg = has && (lab[tid >> 4] != li);
  double eav = has ? (double)EA[i * Mn + tid] : 0.0;
  double s1 = blockReduce16(neg ? eav : 0.0, red);
  double ci = 1.0 / s1;                      // exp(-log_denom)
  double a = ci * eav;
  double p = pexp(a);
  if (has) { sp[tid].x = neg ? a : 0.0; sp[tid].y = neg ? p : 0.0; }
  double t2a = blockReduce16(neg ? p : 0.0, red);
  double t2b = blockReduce16(neg ? p * a : 0.0, red);
  double inv_s2 = 1.0 / t2a;
  double Evi = t2b * inv_s2;
  unsigned long long nm = __ballot(lane < Bn && lab[lane] != li);
  int cnt = 64 - __popcll(nm | 0xFFFF000000000000ull);   // same-label batches

  // ---- sweep positive bj's of this slice; wave w handles j = bj*16 + w ----
  int kb0 = lane >> 4;
  double tsum = 0.0;
  for (int bj = slice; bj < Bn; bj += NS) {
    if (lab[bj] != li) continue;             // uniform LDS test, no divergence
    const float* Ej = E + (bj * 16 + w) * Mn + lane;
    float Evv[12];
    #pragma unroll
    for (int it = 0; it < 12; ++it) Evv[it] = Ej[64 * it];
    double A = 0.0, Bv = 0.0, C = 0.0, D2 = 0.0;
    #pragma unroll
    for (int it = 0; it < 12; ++it) {
      double m = (double)((nm >> (kb0 + 4 * it)) & 1ull);
      double e = ci * (double)Evv[it];
      double wx = pexp(e);
      double wm = wx * m;
      double2 s = sp[lane + 64 * it];
      A  = fma(wm, e, A);
      Bv = fma(wx, s.x, Bv);                 // s.x pre-masked
      C += wm;
      D2 = fma(s.y, e, D2);                  // s.y pre-masked
    }
    #pragma unroll
    for (int o = 32; o > 0; o >>= 1) {
      A  += __shfl_xor(A,  o, 64);
      Bv += __shfl_xor(Bv, o, 64);
      C  += __shfl_xor(C,  o, 64);
      D2 += __shfl_xor(D2, o, 64);
    }
    tsum += (A - Bv) / C - D2 * inv_s2 + Evi;
  }

  // ---- fold 16 wave partials, one float atomic per block ----
  __syncthreads();
  if (lane == 0) red[w] = tsum;
  __syncthreads();
  if (tid == 0) {
    double s = 0.0;
    #pragma unroll
    for (int ww = 0; ww < 16; ++ww) s += red[ww];
    // contribution = 0.5 * s / (Bn * P_i), P_i = 16*cnt  ->  s / (1536*cnt)
    atomicAdd(out, (float)(s / (1536.0 * (double)cnt)));
  }
}

extern "C" void kernel_launch(void* const* d_in, const int* in_sizes, int n_in,
                              void* d_out, int out_size, void* d_ws, size_t ws_size,
                              hipStream_t stream) {
  const float* x   = (const float*)d_in[0];
  const int* label = (const int*)d_in[1];
  float* out = (float*)d_out;

  char* ws = (char*)d_ws;
  size_t off = 0;
  auto alloc = [&](size_t bytes) -> void* {
    void* p = ws + off;
    off = (off + bytes + 255) & ~(size_t)255;
    return p;
  };
  float* EA = (float*)alloc((size_t)Bn * Mn * sizeof(float));
  float* E  = (float*)alloc((size_t)Mn * Mn * sizeof(float));

  kA_gemm<<<dim3(12, 13), 256, 0, stream>>>(x, EA, E, out);
  kB_i<<<dim3(NS, Bn), 1024, 0, stream>>>(EA, E, label, out);
}

// Round 12
// 81.653 us; speedup vs baseline: 1.6364x; 1.0205x over previous
//
#include <hip/hip_runtime.h>
#include <math.h>

#define Bn 48
#define Ln 17
#define Dn 256
#define Mn 768        // Bn*(Ln-1)
#define NS 4          // kB slices per i (blocks = NS*Bn, all active)
#define LDK 264       // LDS row stride in shorts for bf16 tiles (256 + 8)

typedef __attribute__((ext_vector_type(8))) short frag8;   // 8 bf16 = 4 VGPR
typedef __attribute__((ext_vector_type(4))) float fragc;   // C/D accum
typedef __attribute__((ext_vector_type(4))) short short4v;

// float -> bf16 (RNE) as raw short
static __device__ __forceinline__ short f2bf(float f) {
  unsigned u = __float_as_uint(f);
  unsigned r = (u + 0x7FFFu + ((u >> 16) & 1u)) >> 16;
  return (short)r;
}
static __device__ __forceinline__ float bf2f(short h) {
  return __uint_as_float(((unsigned)(unsigned short)h) << 16);
}

// exp(e) for e in [0, ~0.02]; rel err < 3e-15
static __device__ __forceinline__ double pexp(double e) {
  return 1.0 + e*(1.0 + e*(0.5 + e*((1.0/6.0) + e*((1.0/24.0) + e*(1.0/120.0)))));
}

// block-wide sum over 16 waves (1024 threads); safe for back-to-back reuse
static __device__ __forceinline__ double blockReduce16(double v, double* red) {
  __syncthreads();
  #pragma unroll
  for (int o = 32; o > 0; o >>= 1) v += __shfl_down(v, o, 64);
  int lane = threadIdx.x & 63, wid = threadIdx.x >> 6;
  if (lane == 0) red[wid] = v;
  __syncthreads();
  double r = 0.0;
  #pragma unroll
  for (int w = 0; w < 16; ++w) r += red[w];
  return r;
}

// logical row m (0..815: 48 anchors then 768 tokens) -> row in x (B,L,D)
static __device__ __forceinline__ int src_row_m(int m) {
  if (m < Bn) return m * Ln;                 // (b, l=0)
  int t = m - Bn;
  return (t >> 4) * Ln + (t & 15) + 1;       // (b, l=1..16)
}
static __device__ __forceinline__ int src_row_n(int n) {
  return (n >> 4) * Ln + (n & 15) + 1;
}

// ---------- kA: normalize+GEMM via bf16 hi/lo split MFMA + exp epilogue ------
// 64x64 tile, 256 threads (4 waves); wave w -> m-strip w*16..w*16+15.
__global__ __launch_bounds__(256) void kA_gemm(const float* __restrict__ x,
                                               float* __restrict__ EA,
                                               float* __restrict__ E,
                                               float* __restrict__ out) {
  __shared__ short Ahi[64 * LDK];
  __shared__ short Alo[64 * LDK];
  __shared__ short Bhi[64 * LDK];
  __shared__ short Blo[64 * LDK];
  __shared__ float nA[64], nB[64];
  int tid = threadIdx.x;
  if (blockIdx.x == 0 && blockIdx.y == 0 && tid == 0) out[0] = 0.f;
  int m0 = blockIdx.y * 64, n0 = blockIdx.x * 64;

  // ---- staging: thread t -> row r = t>>2, 64-col chunk cq = t&3 ----
  {
    int r = tid >> 2, cq = tid & 3;
    int mrow = m0 + r;
    int gm = (mrow < 816) ? src_row_m(mrow) : 0;
    int gn = src_row_n(n0 + r);
    const float4* pa = (const float4*)(x + gm * Dn) + cq * 16;
    const float4* pb = (const float4*)(x + gn * Dn) + cq * 16;
    float ssa = 0.f, ssb = 0.f;
    #pragma unroll
    for (int c4 = 0; c4 < 16; ++c4) {
      float4 fa = pa[c4];
      float4 fb = pb[c4];
      ssa += fa.x*fa.x + fa.y*fa.y + fa.z*fa.z + fa.w*fa.w;
      ssb += fb.x*fb.x + fb.y*fb.y + fb.z*fb.z + fb.w*fb.w;
      int col = cq * 64 + c4 * 4;
      short4v ah, al, bh, bl;
      ah.x = f2bf(fa.x); al.x = f2bf(fa.x - bf2f(ah.x));
      ah.y = f2bf(fa.y); al.y = f2bf(fa.y - bf2f(ah.y));
      ah.z = f2bf(fa.z); al.z = f2bf(fa.z - bf2f(ah.z));
      ah.w = f2bf(fa.w); al.w = f2bf(fa.w - bf2f(ah.w));
      bh.x = f2bf(fb.x); bl.x = f2bf(fb.x - bf2f(bh.x));
      bh.y = f2bf(fb.y); bl.y = f2bf(fb.y - bf2f(bh.y));
      bh.z = f2bf(fb.z); bl.z = f2bf(fb.z - bf2f(bh.z));
      bh.w = f2bf(fb.w); bl.w = f2bf(fb.w - bf2f(bh.w));
      *(short4v*)&Ahi[r * LDK + col] = ah;
      *(short4v*)&Alo[r * LDK + col] = al;
      *(short4v*)&Bhi[r * LDK + col] = bh;
      *(short4v*)&Blo[r * LDK + col] = bl;
    }
    ssa += __shfl_xor(ssa, 1, 64); ssa += __shfl_xor(ssa, 2, 64);
    ssb += __shfl_xor(ssb, 1, 64); ssb += __shfl_xor(ssb, 2, 64);
    if ((tid & 3) == 0) { nA[r] = ssa; nB[r] = ssb; }
  }
  __syncthreads();

  // ---- MFMA: wave w computes rows w*16..+15 x all 64 cols ----
  int lane = tid & 63, w = tid >> 6;
  int ml = lane & 15, q = lane >> 4;
  fragc acc[4];
  #pragma unroll
  for (int s = 0; s < 4; ++s) acc[s] = (fragc){0.f, 0.f, 0.f, 0.f};
  int arow = (w * 16 + ml) * LDK;
  #pragma unroll
  for (int s = 0; s < 8; ++s) {
    int ko = s * 32 + q * 8;
    frag8 ah = *(const frag8*)&Ahi[arow + ko];
    frag8 al = *(const frag8*)&Alo[arow + ko];
    #pragma unroll
    for (int sub = 0; sub < 4; ++sub) {
      int brow = (sub * 16 + ml) * LDK;
      frag8 bh = *(const frag8*)&Bhi[brow + ko];
      frag8 bl = *(const frag8*)&Blo[brow + ko];
      acc[sub] = __builtin_amdgcn_mfma_f32_16x16x32_bf16(ah, bh, acc[sub], 0, 0, 0);
      acc[sub] = __builtin_amdgcn_mfma_f32_16x16x32_bf16(ah, bl, acc[sub], 0, 0, 0);
      acc[sub] = __builtin_amdgcn_mfma_f32_16x16x32_bf16(al, bh, acc[sub], 0, 0, 0);
    }
  }

  // ---- epilogue: C/D layout col=lane&15, row=q*4+reg; fp64 scale + __expf ----
  double ia[4], ib[4];
  #pragma unroll
  for (int rg = 0; rg < 4; ++rg) ia[rg] = 1.0 / sqrt((double)nA[w * 16 + q * 4 + rg]);
  #pragma unroll
  for (int sub = 0; sub < 4; ++sub) ib[sub] = 1.0 / sqrt((double)nB[sub * 16 + ml]);
  #pragma unroll
  for (int sub = 0; sub < 4; ++sub) {
    int n = n0 + sub * 16 + ml;
    #pragma unroll
    for (int rg = 0; rg < 4; ++rg) {
      int m = m0 + w * 16 + q * 4 + rg;
      if (m < 816) {
        float s = (float)((double)acc[sub][rg] * ia[rg] * ib[sub]);   // T = 1.0
        float ev = __expf(s);
        if (m < Bn) EA[m * Mn + n] = ev;
        else        E[(m - Bn) * Mn + n] = ev;
      }
    }
  }
}

// ---------- kB: grid (NS, Bn) — per-i setup + sweep positive bj; atomic out ----
// t(i,j) = (A - Bv)/C - D2*inv_s2 + Evi
__global__ __launch_bounds__(1024, 2) void kB_i(const float* __restrict__ EA,
                                                const float* __restrict__ E,
                                                const int* __restrict__ label,
                                                float* __restrict__ out) {
  __shared__ double2 sp[Mn];                 // {a masked, pexp(a) masked}
  __shared__ double red[16];
  __shared__ int lab[Bn];
  int slice = blockIdx.x, i = blockIdx.y;
  int tid = threadIdx.x;
  int lane = tid & 63, w = tid >> 6;
  if (tid < Bn) lab[tid] = label[tid];
  __syncthreads();
  int li = lab[i];

  // ---- per-i setup from EA row (tid<768 holds one element in-register) ----
  bool has = (tid < Mn);
  bool neg = has && (lab[tid >> 4] != li);
  double eav = has ? (double)EA[i * Mn + tid] : 0.0;
  double s1 = blockReduce16(neg ? eav : 0.0, red);
  double ci = 1.0 / s1;                      // exp(-log_denom)
  double a = ci * eav;
  double p = pexp(a);
  if (has) { sp[tid].x = neg ? a : 0.0; sp[tid].y = neg ? p : 0.0; }
  double t2a = blockReduce16(neg ? p : 0.0, red);
  double t2b = blockReduce16(neg ? p * a : 0.0, red);
  double inv_s2 = 1.0 / t2a;
  double Evi = t2b * inv_s2;
  unsigned long long nm = __ballot(lane < Bn && lab[lane] != li);
  int cnt = 64 - __popcll(nm | 0xFFFF000000000000ull);   // same-label batches

  // ---- sweep positive bj's of this slice; wave w handles j = bj*16 + w ----
  // lane l covers k = 4l..4l+3 (+256*it): 3 float4 loads, 1 mask bit per it.
  int mb = lane >> 2;                        // batch index base (4l >> 4)
  double tsum = 0.0;
  for (int bj = slice; bj < Bn; bj += NS) {
    if (lab[bj] != li) continue;             // uniform LDS test, no divergence
    const float4* Ej4 = (const float4*)(E + (bj * 16 + w) * Mn) + lane;
    float4 ev[3];
    ev[0] = Ej4[0];
    ev[1] = Ej4[64];
    ev[2] = Ej4[128];
    double A = 0.0, Bv = 0.0, C = 0.0, D2 = 0.0;
    #pragma unroll
    for (int it = 0; it < 3; ++it) {
      double m = (double)((nm >> (mb + 16 * it)) & 1ull);
      float evv[4] = {ev[it].x, ev[it].y, ev[it].z, ev[it].w};
      #pragma unroll
      for (int c = 0; c < 4; ++c) {
        double e = ci * (double)evv[c];
        double wx = pexp(e);
        double wm = wx * m;
        double2 s = sp[4 * lane + 256 * it + c];
        A  = fma(wm, e, A);
        Bv = fma(wx, s.x, Bv);               // s.x pre-masked
        C += wm;
        D2 = fma(s.y, e, D2);                // s.y pre-masked
      }
    }
    #pragma unroll
    for (int o = 32; o > 0; o >>= 1) {
      A  += __shfl_xor(A,  o, 64);
      Bv += __shfl_xor(Bv, o, 64);
      C  += __shfl_xor(C,  o, 64);
      D2 += __shfl_xor(D2, o, 64);
    }
    tsum += (A - Bv) / C - D2 * inv_s2 + Evi;
  }

  // ---- fold 16 wave partials, one float atomic per block ----
  __syncthreads();
  if (lane == 0) red[w] = tsum;
  __syncthreads();
  if (tid == 0) {
    double s = 0.0;
    #pragma unroll
    for (int ww = 0; ww < 16; ++ww) s += red[ww];
    // contribution = 0.5 * s / (Bn * P_i), P_i = 16*cnt  ->  s / (1536*cnt)
    atomicAdd(out, (float)(s / (1536.0 * (double)cnt)));
  }
}

extern "C" void kernel_launch(void* const* d_in, const int* in_sizes, int n_in,
                              void* d_out, int out_size, void* d_ws, size_t ws_size,
                              hipStream_t stream) {
  const float* x   = (const float*)d_in[0];
  const int* label = (const int*)d_in[1];
  float* out = (float*)d_out;

  char* ws = (char*)d_ws;
  size_t off = 0;
  auto alloc = [&](size_t bytes) -> void* {
    void* p = ws + off;
    off = (off + bytes + 255) & ~(size_t)255;
    return p;
  };
  float* EA = (float*)alloc((size_t)Bn * Mn * sizeof(float));
  float* E  = (float*)alloc((size_t)Mn * Mn * sizeof(float));

  kA_gemm<<<dim3(12, 13), 256, 0, stream>>>(x, EA, E, out);
  kB_i<<<dim3(NS, Bn), 1024, 0, stream>>>(EA, E, label, out);
}